// Round 4
// baseline (387.758 us; speedup 1.0000x reference)
//
#include <hip/hip_runtime.h>

#define B_ROWS 32768
#define D_DIM 768
#define H_DIM 64
#define E_NUM 7
#define BM 64
#define PERM_CAP (B_ROWS + E_NUM * BM)   // 33216
#define NBLOCKS_MAIN (PERM_CAP / BM)     // 519
#define W_ELEMS (E_NUM * D_DIM * H_DIM)  // 344064
#define INIT_BLOCKS ((PERM_CAP + 255) / 256)        // 130
#define CONV_BLOCKS ((2 * W_ELEMS + 255) / 256)     // 2688

// ---- ws layout (bytes) ----
#define WS_COUNTS 0
#define WS_BASE   64
#define WS_CURSOR 128
#define WS_PERM   256
#define WS_W      133120                  // 256 + 33216*4 (256B aligned)
#define WS_WSZ    (W_ELEMS * 2)           // 688128 bytes per weight plane
#define WS_NEEDED (WS_W + 4 * WS_WSZ)     // 2,885,632

typedef __attribute__((ext_vector_type(8))) short short8;
typedef __attribute__((ext_vector_type(8))) __bf16 bf16x8;
typedef __attribute__((ext_vector_type(4))) float f32x4;

__device__ __forceinline__ unsigned short f2bf(float f) {
  unsigned int u = __float_as_uint(f);
  unsigned int r = (u + 0x7fffu + ((u >> 16) & 1u)) >> 16;
  return (unsigned short)r;
}
__device__ __forceinline__ float bf2f(unsigned short s) {
  return __uint_as_float(((unsigned int)s) << 16);
}
__device__ __forceinline__ f32x4 mfma16(short8 a, short8 b, f32x4 c) {
  return __builtin_amdgcn_mfma_f32_16x16x32_bf16(
      __builtin_bit_cast(bf16x8, a), __builtin_bit_cast(bf16x8, b), c, 0, 0, 0);
}

// ---------------- prep: perm/counts init + coalesced weight split ----------------
// W1 (E,D,H) -> w1{hi,lo}[e][h][d]; W2 (E,H,D) -> w2{hi,lo}[e][d][h].
// Reads are coalesced (source order); 2B writes scatter but don't stall.
__global__ void k_prep(int* __restrict__ counts, int* __restrict__ perm,
                       const float* __restrict__ W1, const float* __restrict__ W2,
                       short* __restrict__ w1hi, short* __restrict__ w1lo,
                       short* __restrict__ w2hi, short* __restrict__ w2lo) {
  const int bid = blockIdx.x;
  if (bid < INIT_BLOCKS) {
    int i = bid * 256 + threadIdx.x;
    if (i < PERM_CAP) perm[i] = -1;
    if (bid == 0 && threadIdx.x < 16) counts[threadIdx.x] = 0;
    return;
  }
  int idx = (bid - INIT_BLOCKS) * 256 + threadIdx.x;
  if (idx < W_ELEMS) {
    // source [e][d][h], contiguous read
    int e = idx / (D_DIM * H_DIM);
    int rem = idx - e * (D_DIM * H_DIM);
    int d = rem / H_DIM;
    int h = rem - d * H_DIM;
    float v = W1[idx];
    unsigned short hi = f2bf(v);
    size_t o = (size_t)e * H_DIM * D_DIM + (size_t)h * D_DIM + d;
    w1hi[o] = (short)hi;
    w1lo[o] = (short)f2bf(v - bf2f(hi));
  } else if (idx < 2 * W_ELEMS) {
    // source [e][h][d], contiguous read
    int o0 = idx - W_ELEMS;
    int e = o0 / (H_DIM * D_DIM);
    int rem = o0 - e * (H_DIM * D_DIM);
    int h = rem / D_DIM;
    int d = rem - h * D_DIM;
    float v = W2[o0];
    unsigned short hi = f2bf(v);
    size_t o = (size_t)e * D_DIM * H_DIM + (size_t)d * H_DIM + h;
    w2hi[o] = (short)hi;
    w2lo[o] = (short)f2bf(v - bf2f(hi));
  }
}

// ---------------- routing kernels ----------------
__global__ void k_hist(const int* __restrict__ eid, int* __restrict__ counts) {
  __shared__ int lc[E_NUM];
  if (threadIdx.x < E_NUM) lc[threadIdx.x] = 0;
  __syncthreads();
  int e = eid[blockIdx.x * 256 + threadIdx.x];
  e = e < 0 ? 0 : (e >= E_NUM ? E_NUM - 1 : e);
  atomicAdd(&lc[e], 1);
  __syncthreads();
  if (threadIdx.x < E_NUM) atomicAdd(&counts[threadIdx.x], lc[threadIdx.x]);
}

__global__ void k_scan(const int* __restrict__ counts, int* __restrict__ base,
                       int* __restrict__ cursor) {
  if (threadIdx.x == 0) {
    int run = 0;
    for (int e = 0; e < E_NUM; ++e) {
      base[e] = run;
      cursor[e] = run;
      run += ((counts[e] + BM - 1) / BM) * BM;
    }
    base[E_NUM] = run;
  }
}

__global__ void k_scatter(const int* __restrict__ eid, int* __restrict__ cursor,
                          int* __restrict__ perm) {
  __shared__ int lc[E_NUM];
  __shared__ int lb[E_NUM];
  if (threadIdx.x < E_NUM) lc[threadIdx.x] = 0;
  __syncthreads();
  int i = blockIdx.x * 256 + threadIdx.x;
  int e = eid[i];
  e = e < 0 ? 0 : (e >= E_NUM ? E_NUM - 1 : e);
  int lpos = atomicAdd(&lc[e], 1);
  __syncthreads();
  if (threadIdx.x < E_NUM) lb[threadIdx.x] = atomicAdd(&cursor[threadIdx.x], lc[threadIdx.x]);
  __syncthreads();
  perm[lb[e] + lpos] = i;
}

// ---------------- main fused kernel ----------------
// 519 blocks x 512 thr (8 waves). Block = 64 permuted rows, one expert.
// wave (r = wid&3, half = wid>>2):
//   GEMM1: rows r*16, n-tiles {half*2, half*2+1}; K=768 fully unrolled.
//   GEMM2: rows r*16, col-half half*384, 24 c-tiles fully unrolled.
__global__ __launch_bounds__(512, 4) void k_adapter(
    const float* __restrict__ x, const float* __restrict__ b1,
    const float* __restrict__ b2, const short* __restrict__ w1hi,
    const short* __restrict__ w1lo, const short* __restrict__ w2hi,
    const short* __restrict__ w2lo, const int* __restrict__ base,
    const int* __restrict__ perm, float* __restrict__ out) {
  // stride 72 shorts -> 144B rows (16B aligned, 2-way bank alias only = free)
  __shared__ __align__(16) short hl_hi[4][16][72];
  __shared__ __align__(16) short hl_lo[4][16][72];

  const int tid = threadIdx.x;
  const int wid = tid >> 6;
  const int lane = tid & 63;
  const int l15 = lane & 15;
  const int kg = lane >> 4;   // 0..3
  const int r = wid & 3;      // row-frag
  const int half = wid >> 2;  // n-half / col-half
  const int m0 = blockIdx.x * BM;

  int e = 0;
#pragma unroll
  for (int i = 1; i < E_NUM; ++i)
    if (m0 >= base[i]) e = i;

  // ---- GEMM1: h[16x32] = x[16x768] @ W1[e][:, half*32 : half*32+32] ----
  const int ar = perm[m0 + r * 16 + l15];
  const float* xrow = x + (size_t)(ar < 0 ? 0 : ar) * D_DIM;
  const short* w1h = w1hi + (size_t)e * H_DIM * D_DIM;
  const short* w1l = w1lo + (size_t)e * H_DIM * D_DIM;

  f32x4 acc1[2] = {{0.f, 0.f, 0.f, 0.f}, {0.f, 0.f, 0.f, 0.f}};

#pragma unroll
  for (int kt = 0; kt < D_DIM; kt += 32) {
    const int k0 = kt + kg * 8;
    f32x4 xa = *reinterpret_cast<const f32x4*>(xrow + k0);
    f32x4 xb = *reinterpret_cast<const f32x4*>(xrow + k0 + 4);
    short8 ahi, alo;
#pragma unroll
    for (int i = 0; i < 4; ++i) {
      unsigned short h0 = f2bf(xa[i]);
      ahi[i] = (short)h0;
      alo[i] = (short)f2bf(xa[i] - bf2f(h0));
      unsigned short h1 = f2bf(xb[i]);
      ahi[4 + i] = (short)h1;
      alo[4 + i] = (short)f2bf(xb[i] - bf2f(h1));
    }
#pragma unroll
    for (int nn = 0; nn < 2; ++nn) {
      const int n = half * 2 + nn;
      const size_t boff = (size_t)(n * 16 + l15) * D_DIM + k0;
      short8 bhi = *reinterpret_cast<const short8*>(w1h + boff);
      short8 blo = *reinterpret_cast<const short8*>(w1l + boff);
      acc1[nn] = mfma16(ahi, bhi, acc1[nn]);
      acc1[nn] = mfma16(ahi, blo, acc1[nn]);
      acc1[nn] = mfma16(alo, bhi, acc1[nn]);
    }
  }

  // bias + relu, split to bf16 hi/lo, park in LDS (re-layout C->A-frag)
#pragma unroll
  for (int nn = 0; nn < 2; ++nn) {
    const int col = (half * 2 + nn) * 16 + l15;
    const float bv = b1[e * H_DIM + col];
#pragma unroll
    for (int j = 0; j < 4; ++j) {
      float v = acc1[nn][j] + bv;
      v = v > 0.f ? v : 0.f;
      unsigned short hh = f2bf(v);
      const int row = kg * 4 + j;
      hl_hi[r][row][col] = (short)hh;
      hl_lo[r][row][col] = (short)f2bf(v - bf2f(hh));
    }
  }
  __syncthreads();

  // ---- GEMM2: out[16 x 384-half] = relu(h) @ W2[e] + b2 + x ----
  short8 a2h[2], a2l[2];
#pragma unroll
  for (int ks = 0; ks < 2; ++ks) {
    a2h[ks] = *reinterpret_cast<const short8*>(&hl_hi[r][l15][ks * 32 + kg * 8]);
    a2l[ks] = *reinterpret_cast<const short8*>(&hl_lo[r][l15][ks * 32 + kg * 8]);
  }

  int crow[4];
#pragma unroll
  for (int j = 0; j < 4; ++j) crow[j] = perm[m0 + r * 16 + kg * 4 + j];

  const short* w2h = w2hi + (size_t)e * D_DIM * H_DIM;
  const short* w2l = w2lo + (size_t)e * D_DIM * H_DIM;
  const float* b2e = b2 + e * D_DIM;
  const int c0 = half * (D_DIM / 2);

#pragma unroll
  for (int ct = 0; ct < D_DIM / 32; ++ct) {
    const int col = c0 + ct * 16 + l15;
    f32x4 acc2 = {0.f, 0.f, 0.f, 0.f};
#pragma unroll
    for (int ks = 0; ks < 2; ++ks) {
      const size_t boff = (size_t)col * H_DIM + ks * 32 + kg * 8;
      short8 bhi = *reinterpret_cast<const short8*>(w2h + boff);
      short8 blo = *reinterpret_cast<const short8*>(w2l + boff);
      acc2 = mfma16(a2h[ks], bhi, acc2);
      acc2 = mfma16(a2h[ks], blo, acc2);
      acc2 = mfma16(a2l[ks], bhi, acc2);
    }
    const float bv = b2e[col];
#pragma unroll
    for (int j = 0; j < 4; ++j) {
      const int rr = crow[j];
      if (rr >= 0) {
        const size_t o = (size_t)rr * D_DIM + col;
        out[o] = acc2[j] + bv + x[o];
      }
    }
  }
}

// ---------------- fp32 fallback (used only if ws too small) ----------------
__global__ void k_fallback(const float* __restrict__ x, const int* __restrict__ eid,
                           const float* __restrict__ W1, const float* __restrict__ b1,
                           const float* __restrict__ W2, const float* __restrict__ b2,
                           float* __restrict__ out) {
  __shared__ float xs[D_DIM];
  __shared__ float hs[H_DIM];
  const int row = blockIdx.x;
  int e = eid[row];
  e = e < 0 ? 0 : (e >= E_NUM ? E_NUM - 1 : e);
  const float* xr = x + (size_t)row * D_DIM;
  for (int i = threadIdx.x; i < D_DIM; i += 256) xs[i] = xr[i];
  __syncthreads();
  if (threadIdx.x < H_DIM) {
    const float* w = W1 + (size_t)e * D_DIM * H_DIM + threadIdx.x;
    float acc = b1[e * H_DIM + threadIdx.x];
    for (int d = 0; d < D_DIM; ++d) acc += xs[d] * w[(size_t)d * H_DIM];
    hs[threadIdx.x] = acc > 0.f ? acc : 0.f;
  }
  __syncthreads();
  for (int c = threadIdx.x; c < D_DIM; c += 256) {
    const float* w = W2 + (size_t)e * H_DIM * D_DIM + c;
    float acc = b2[e * D_DIM + c];
    for (int h = 0; h < H_DIM; ++h) acc += hs[h] * w[(size_t)h * D_DIM];
    out[(size_t)row * D_DIM + c] = xs[c] + acc;
  }
}

extern "C" void kernel_launch(void* const* d_in, const int* in_sizes, int n_in,
                              void* d_out, int out_size, void* d_ws, size_t ws_size,
                              hipStream_t stream) {
  const float* x = (const float*)d_in[0];
  const int* eid = (const int*)d_in[1];
  const float* W1 = (const float*)d_in[2];
  const float* b1 = (const float*)d_in[3];
  const float* W2 = (const float*)d_in[4];
  const float* b2 = (const float*)d_in[5];
  float* out = (float*)d_out;

  if (ws_size < (size_t)WS_NEEDED) {
    k_fallback<<<B_ROWS, 256, 0, stream>>>(x, eid, W1, b1, W2, b2, out);
    return;
  }

  char* ws = (char*)d_ws;
  int* counts = (int*)(ws + WS_COUNTS);
  int* base = (int*)(ws + WS_BASE);
  int* cursor = (int*)(ws + WS_CURSOR);
  int* perm = (int*)(ws + WS_PERM);
  short* w1hi = (short*)(ws + WS_W);
  short* w1lo = (short*)(ws + WS_W + WS_WSZ);
  short* w2hi = (short*)(ws + WS_W + 2 * WS_WSZ);
  short* w2lo = (short*)(ws + WS_W + 3 * WS_WSZ);

  k_prep<<<INIT_BLOCKS + CONV_BLOCKS, 256, 0, stream>>>(counts, perm, W1, W2,
                                                        w1hi, w1lo, w2hi, w2lo);
  k_hist<<<B_ROWS / 256, 256, 0, stream>>>(eid, counts);
  k_scan<<<1, 64, 0, stream>>>(counts, base, cursor);
  k_scatter<<<B_ROWS / 256, 256, 0, stream>>>(eid, cursor, perm);
  k_adapter<<<NBLOCKS_MAIN, 512, 0, stream>>>(x, b1, b2, w1hi, w1lo, w2hi, w2lo,
                                              base, perm, out);
}

// Round 5
// 293.964 us; speedup vs baseline: 1.3191x; 1.3191x over previous
//
#include <hip/hip_runtime.h>

#define B_ROWS 32768
#define D_DIM 768
#define H_DIM 64
#define E_NUM 7
#define BM 64
#define PERM_CAP (B_ROWS + E_NUM * BM)   // 33216
#define NBLOCKS_MAIN (PERM_CAP / BM)     // 519
#define W_ELEMS (E_NUM * D_DIM * H_DIM)  // 344064

#define PREP_INIT ((PERM_CAP + 255) / 256)  // 130
#define PREP_W1 (E_NUM * 24)                // 168  (e, kt: 32-d slab, all H)
#define PREP_W2 (E_NUM * 12)                // 84   (e, ctb: 64-d slab, all H)

// ---- ws layout (bytes) ----
#define WS_COUNTS 0
#define WS_BASE   64
#define WS_CURSOR 128
#define WS_PERM   256
#define WS_W      133120                    // 256-aligned
#define WS_WF     1376256                   // shorts per packed weight buffer *2B
#define WS_NEEDED (WS_W + 2 * WS_WF)        // 2,885,632

typedef __attribute__((ext_vector_type(8))) short short8;
typedef __attribute__((ext_vector_type(8))) __bf16 bf16x8;
typedef __attribute__((ext_vector_type(4))) float f32x4;

__device__ __forceinline__ unsigned short f2bf(float f) {
  unsigned int u = __float_as_uint(f);
  unsigned int r = (u + 0x7fffu + ((u >> 16) & 1u)) >> 16;
  return (unsigned short)r;
}
__device__ __forceinline__ float bf2f(unsigned short s) {
  return __uint_as_float(((unsigned int)s) << 16);
}
__device__ __forceinline__ f32x4 mfma16(short8 a, short8 b, f32x4 c) {
  return __builtin_amdgcn_mfma_f32_16x16x32_bf16(
      __builtin_bit_cast(bf16x8, a), __builtin_bit_cast(bf16x8, b), c, 0, 0, 0);
}

// ---------------- prep: init + fragment-order weight packing ----------------
// w1f layout (shorts): ((((e*4+n)*24+kt)*2+plane)*64+lane)*8+j
//   element = W1[e][d=kt*32+(lane>>4)*8+j][h=n*16+(lane&15)]
// w2f layout (shorts): ((((e*48+ct)*2+ks)*2+plane)*64+lane)*8+j
//   element = W2[e][h=ks*32+(lane>>4)*8+j][d=ct*16+(lane&15)]
// Both give 1KB-contiguous per-wave fragment loads in the main kernel.
__global__ void k_prep(int* __restrict__ counts, int* __restrict__ perm,
                       const float* __restrict__ W1, const float* __restrict__ W2,
                       short* __restrict__ w1f, short* __restrict__ w2f) {
  __shared__ __align__(16) float tile[64][65];
  const int bid = blockIdx.x;
  const int t = threadIdx.x;

  if (bid < PREP_INIT) {
    int i = bid * 256 + t;
    if (i < PERM_CAP) perm[i] = -1;
    if (bid == 0 && t < 16) counts[t] = 0;
    return;
  }
  if (bid < PREP_INIT + PREP_W1) {
    const int b = bid - PREP_INIT;
    const int e = b / 24, kt = b % 24;
    // read 32 d-rows x 64 h, coalesced f32x4
    {
      const int d = t >> 3, hc = (t & 7) * 8;
      const float* src = W1 + ((size_t)(e * D_DIM + kt * 32 + d)) * H_DIM + hc;
      f32x4 v0 = *reinterpret_cast<const f32x4*>(src);
      f32x4 v1 = *reinterpret_cast<const f32x4*>(src + 4);
#pragma unroll
      for (int i = 0; i < 4; ++i) {
        tile[d][hc + i] = v0[i];
        tile[d][hc + 4 + i] = v1[i];
      }
    }
    __syncthreads();
    // write fragment-order, coalesced 16B
    {
      const int n = t >> 6, lane = t & 63;
      const int kgo = lane >> 4, l15o = lane & 15;
      short8 hi8, lo8;
#pragma unroll
      for (int j = 0; j < 8; ++j) {
        float v = tile[kgo * 8 + j][n * 16 + l15o];
        unsigned short h = f2bf(v);
        hi8[j] = (short)h;
        lo8[j] = (short)f2bf(v - bf2f(h));
      }
      short* dst = w1f + ((size_t)(((e * 4 + n) * 24 + kt) * 2) << 9) + (lane << 3);
      *reinterpret_cast<short8*>(dst) = hi8;
      *reinterpret_cast<short8*>(dst + 512) = lo8;
    }
    return;
  }
  {
    const int b = bid - PREP_INIT - PREP_W1;
    const int e = b / 12, ctb = b % 12;
    // read 64 h-rows x 64 d, coalesced f32x4
    {
      const int h = t >> 2, dc = (t & 3) * 16;
      const float* src = W2 + ((size_t)(e * H_DIM + h)) * D_DIM + ctb * 64 + dc;
#pragma unroll
      for (int k = 0; k < 4; ++k) {
        f32x4 v = *reinterpret_cast<const f32x4*>(src + k * 4);
#pragma unroll
        for (int i = 0; i < 4; ++i) tile[h][dc + k * 4 + i] = v[i];
      }
    }
    __syncthreads();
    {
      const int ct4 = t >> 6, lane = t & 63;
      const int kgo = lane >> 4, l15o = lane & 15;
      const int ct = ctb * 4 + ct4;
#pragma unroll
      for (int ks = 0; ks < 2; ++ks) {
        short8 hi8, lo8;
#pragma unroll
        for (int j = 0; j < 8; ++j) {
          float v = tile[ks * 32 + kgo * 8 + j][ct4 * 16 + l15o];
          unsigned short h = f2bf(v);
          hi8[j] = (short)h;
          lo8[j] = (short)f2bf(v - bf2f(h));
        }
        short* dst = w2f + ((size_t)(((e * 48 + ct) * 2 + ks) * 2) << 9) + (lane << 3);
        *reinterpret_cast<short8*>(dst) = hi8;
        *reinterpret_cast<short8*>(dst + 512) = lo8;
      }
    }
    return;
  }
}

// ---------------- routing kernels ----------------
__global__ void k_hist(const int* __restrict__ eid, int* __restrict__ counts) {
  __shared__ int lc[E_NUM];
  if (threadIdx.x < E_NUM) lc[threadIdx.x] = 0;
  __syncthreads();
  int e = eid[blockIdx.x * 256 + threadIdx.x];
  e = e < 0 ? 0 : (e >= E_NUM ? E_NUM - 1 : e);
  atomicAdd(&lc[e], 1);
  __syncthreads();
  if (threadIdx.x < E_NUM) atomicAdd(&counts[threadIdx.x], lc[threadIdx.x]);
}

__global__ void k_scan(const int* __restrict__ counts, int* __restrict__ base,
                       int* __restrict__ cursor) {
  if (threadIdx.x == 0) {
    int run = 0;
    for (int e = 0; e < E_NUM; ++e) {
      base[e] = run;
      cursor[e] = run;
      run += ((counts[e] + BM - 1) / BM) * BM;
    }
    base[E_NUM] = run;
  }
}

__global__ void k_scatter(const int* __restrict__ eid, int* __restrict__ cursor,
                          int* __restrict__ perm) {
  __shared__ int lc[E_NUM];
  __shared__ int lb[E_NUM];
  if (threadIdx.x < E_NUM) lc[threadIdx.x] = 0;
  __syncthreads();
  int i = blockIdx.x * 256 + threadIdx.x;
  int e = eid[i];
  e = e < 0 ? 0 : (e >= E_NUM ? E_NUM - 1 : e);
  int lpos = atomicAdd(&lc[e], 1);
  __syncthreads();
  if (threadIdx.x < E_NUM) lb[threadIdx.x] = atomicAdd(&cursor[threadIdx.x], lc[threadIdx.x]);
  __syncthreads();
  perm[lb[e] + lpos] = i;
}

// ---------------- main fused kernel ----------------
// 519 blocks x 512 thr (8 waves). Block = 64 permuted rows, one expert.
// wave (r = wid&3, half = wid>>2): GEMM1 rows r*16, n-half; GEMM2 rows r*16, col-half.
// Weight loads are 1KB contiguous per wave; 1-deep register prefetch pipeline.
__global__ __launch_bounds__(512, 4) void k_adapter(
    const float* __restrict__ x, const float* __restrict__ b1,
    const float* __restrict__ b2, const short* __restrict__ w1f,
    const short* __restrict__ w2f, const int* __restrict__ base,
    const int* __restrict__ perm, float* __restrict__ out) {
  __shared__ __align__(16) short hl_hi[4][16][72];
  __shared__ __align__(16) short hl_lo[4][16][72];
  __shared__ __align__(16) float ldsT[8][16][68];  // per-wave epilogue transpose

  const int tid = threadIdx.x;
  const int wid = tid >> 6;
  const int lane = tid & 63;
  const int l15 = lane & 15;
  const int kg = lane >> 4;
  const int r = wid & 3;
  const int half = wid >> 2;
  const int m0 = blockIdx.x * BM;

  int e = 0;
#pragma unroll
  for (int i = 1; i < E_NUM; ++i)
    if (m0 >= base[i]) e = i;

  // ---- GEMM1: h[16x32] = x[16x768] @ W1[e][:, half*32 : +32] ----
  const int ar = perm[m0 + r * 16 + l15];
  const float* xrow = x + (size_t)(ar < 0 ? 0 : ar) * D_DIM;
  const short* w1e = w1f + (size_t)e * 98304;
  const int n0 = half * 2, n1 = half * 2 + 1;
#define W1P(n_, kt_) (w1e + (((size_t)((n_)*24 + (kt_)) * 2) << 9) + (lane << 3))

  f32x4 acc1[2] = {{0.f, 0.f, 0.f, 0.f}, {0.f, 0.f, 0.f, 0.f}};

  f32x4 nxa = *reinterpret_cast<const f32x4*>(xrow + kg * 8);
  f32x4 nxb = *reinterpret_cast<const f32x4*>(xrow + kg * 8 + 4);
  short8 nb0 = *reinterpret_cast<const short8*>(W1P(n0, 0));
  short8 nb1 = *reinterpret_cast<const short8*>(W1P(n0, 0) + 512);
  short8 nb2 = *reinterpret_cast<const short8*>(W1P(n1, 0));
  short8 nb3 = *reinterpret_cast<const short8*>(W1P(n1, 0) + 512);

#pragma unroll
  for (int kt = 0; kt < 24; ++kt) {
    f32x4 xa = nxa, xb = nxb;
    short8 b0h = nb0, b0l = nb1, b1h = nb2, b1l = nb3;
    if (kt < 23) {
      const int k0 = (kt + 1) * 32 + kg * 8;
      nxa = *reinterpret_cast<const f32x4*>(xrow + k0);
      nxb = *reinterpret_cast<const f32x4*>(xrow + k0 + 4);
      nb0 = *reinterpret_cast<const short8*>(W1P(n0, kt + 1));
      nb1 = *reinterpret_cast<const short8*>(W1P(n0, kt + 1) + 512);
      nb2 = *reinterpret_cast<const short8*>(W1P(n1, kt + 1));
      nb3 = *reinterpret_cast<const short8*>(W1P(n1, kt + 1) + 512);
    }
    short8 ahi, alo;
#pragma unroll
    for (int i = 0; i < 4; ++i) {
      unsigned short h0 = f2bf(xa[i]);
      ahi[i] = (short)h0;
      alo[i] = (short)f2bf(xa[i] - bf2f(h0));
      unsigned short h1 = f2bf(xb[i]);
      ahi[4 + i] = (short)h1;
      alo[4 + i] = (short)f2bf(xb[i] - bf2f(h1));
    }
    acc1[0] = mfma16(ahi, b0h, acc1[0]);
    acc1[0] = mfma16(alo, b0h, acc1[0]);
    acc1[0] = mfma16(ahi, b0l, acc1[0]);
    acc1[1] = mfma16(ahi, b1h, acc1[1]);
    acc1[1] = mfma16(alo, b1h, acc1[1]);
    acc1[1] = mfma16(ahi, b1l, acc1[1]);
  }

  // bias + relu, split hi/lo, park in LDS (C-frag -> A-frag re-layout)
#pragma unroll
  for (int nn = 0; nn < 2; ++nn) {
    const int col = (half * 2 + nn) * 16 + l15;
    const float bv = b1[e * H_DIM + col];
#pragma unroll
    for (int j = 0; j < 4; ++j) {
      float v = acc1[nn][j] + bv;
      v = v > 0.f ? v : 0.f;
      unsigned short hh = f2bf(v);
      hl_hi[r][kg * 4 + j][col] = (short)hh;
      hl_lo[r][kg * 4 + j][col] = (short)f2bf(v - bf2f(hh));
    }
  }

  // prefetch GEMM2 weights (independent of barrier)
  const short* w2e = w2f + (size_t)e * 98304;
  const int ct0 = half * 24;
#define W2P(ct_, ks_) (w2e + (((size_t)((ct_)*2 + (ks_)) * 2) << 9) + (lane << 3))
  short8 nwh = *reinterpret_cast<const short8*>(W2P(ct0, 0));
  short8 nwl = *reinterpret_cast<const short8*>(W2P(ct0, 0) + 512);

  const int grow = perm[m0 + r * 16 + (lane >> 2)];

  __syncthreads();

  short8 a2h[2], a2l[2];
#pragma unroll
  for (int ks = 0; ks < 2; ++ks) {
    a2h[ks] = *reinterpret_cast<const short8*>(&hl_hi[r][l15][ks * 32 + kg * 8]);
    a2l[ks] = *reinterpret_cast<const short8*>(&hl_lo[r][l15][ks * 32 + kg * 8]);
  }

  const float* b2e = b2 + e * D_DIM;
  const int tr = lane >> 2, cq = lane & 3;
  const float* xr2 = x + (size_t)(grow < 0 ? 0 : grow) * D_DIM;
  float* orow = out + (size_t)(grow < 0 ? 0 : grow) * D_DIM;

  // ---- GEMM2: 6 groups of 4 ct-tiles (64 cols each) ----
#pragma unroll
  for (int g = 0; g < 6; ++g) {
    f32x4 acc2[4];
#pragma unroll
    for (int t = 0; t < 8; ++t) {
      const int ct4 = t >> 1, ks = t & 1;
      short8 wh = nwh, wl = nwl;
      if (!(g == 5 && t == 7)) {
        const int t2 = t + 1;
        const int g2 = (t2 == 8) ? g + 1 : g;
        const int tt = t2 & 7;
        const int nct = ct0 + g2 * 4 + (tt >> 1);
        const int nks = tt & 1;
        nwh = *reinterpret_cast<const short8*>(W2P(nct, nks));
        nwl = *reinterpret_cast<const short8*>(W2P(nct, nks) + 512);
      }
      if (ks == 0) acc2[ct4] = (f32x4){0.f, 0.f, 0.f, 0.f};
      acc2[ct4] = mfma16(a2h[ks], wh, acc2[ct4]);
      acc2[ct4] = mfma16(a2l[ks], wh, acc2[ct4]);
      acc2[ct4] = mfma16(a2h[ks], wl, acc2[ct4]);
    }
    // transpose via per-wave LDS: lane -> 16 consecutive cols of one row
#pragma unroll
    for (int ct4 = 0; ct4 < 4; ++ct4)
#pragma unroll
      for (int j = 0; j < 4; ++j) ldsT[wid][kg * 4 + j][ct4 * 16 + l15] = acc2[ct4][j];
    asm volatile("s_waitcnt lgkmcnt(0)" ::: "memory");
    __builtin_amdgcn_sched_barrier(0);

    const int colbase = (half * 6 + g) * 64 + cq * 16;
    f32x4 y0 = *reinterpret_cast<const f32x4*>(&ldsT[wid][tr][cq * 16 + 0]);
    f32x4 y1 = *reinterpret_cast<const f32x4*>(&ldsT[wid][tr][cq * 16 + 4]);
    f32x4 y2 = *reinterpret_cast<const f32x4*>(&ldsT[wid][tr][cq * 16 + 8]);
    f32x4 y3 = *reinterpret_cast<const f32x4*>(&ldsT[wid][tr][cq * 16 + 12]);
    if (grow >= 0) {
#pragma unroll
      for (int k = 0; k < 4; ++k) {
        f32x4 y = k == 0 ? y0 : (k == 1 ? y1 : (k == 2 ? y2 : y3));
        f32x4 bv = *reinterpret_cast<const f32x4*>(b2e + colbase + k * 4);
        f32x4 xv = *reinterpret_cast<const f32x4*>(xr2 + colbase + k * 4);
        f32x4 o = y + bv + xv;
        *reinterpret_cast<f32x4*>(orow + colbase + k * 4) = o;
      }
    }
  }
#undef W1P
#undef W2P
}

// ---------------- fp32 fallback (used only if ws too small) ----------------
__global__ void k_fallback(const float* __restrict__ x, const int* __restrict__ eid,
                           const float* __restrict__ W1, const float* __restrict__ b1,
                           const float* __restrict__ W2, const float* __restrict__ b2,
                           float* __restrict__ out) {
  __shared__ float xs[D_DIM];
  __shared__ float hs[H_DIM];
  const int row = blockIdx.x;
  int e = eid[row];
  e = e < 0 ? 0 : (e >= E_NUM ? E_NUM - 1 : e);
  const float* xr = x + (size_t)row * D_DIM;
  for (int i = threadIdx.x; i < D_DIM; i += 256) xs[i] = xr[i];
  __syncthreads();
  if (threadIdx.x < H_DIM) {
    const float* w = W1 + (size_t)e * D_DIM * H_DIM + threadIdx.x;
    float acc = b1[e * H_DIM + threadIdx.x];
    for (int d = 0; d < D_DIM; ++d) acc += xs[d] * w[(size_t)d * H_DIM];
    hs[threadIdx.x] = acc > 0.f ? acc : 0.f;
  }
  __syncthreads();
  for (int c = threadIdx.x; c < D_DIM; c += 256) {
    const float* w = W2 + (size_t)e * H_DIM * D_DIM + c;
    float acc = b2[e * D_DIM + c];
    for (int h = 0; h < H_DIM; ++h) acc += hs[h] * w[(size_t)h * D_DIM];
    out[(size_t)row * D_DIM + c] = xs[c] + acc;
  }
}

extern "C" void kernel_launch(void* const* d_in, const int* in_sizes, int n_in,
                              void* d_out, int out_size, void* d_ws, size_t ws_size,
                              hipStream_t stream) {
  const float* x = (const float*)d_in[0];
  const int* eid = (const int*)d_in[1];
  const float* W1 = (const float*)d_in[2];
  const float* b1 = (const float*)d_in[3];
  const float* W2 = (const float*)d_in[4];
  const float* b2 = (const float*)d_in[5];
  float* out = (float*)d_out;

  if (ws_size < (size_t)WS_NEEDED) {
    k_fallback<<<B_ROWS, 256, 0, stream>>>(x, eid, W1, b1, W2, b2, out);
    return;
  }

  char* ws = (char*)d_ws;
  int* counts = (int*)(ws + WS_COUNTS);
  int* base = (int*)(ws + WS_BASE);
  int* cursor = (int*)(ws + WS_CURSOR);
  int* perm = (int*)(ws + WS_PERM);
  short* w1f = (short*)(ws + WS_W);
  short* w2f = (short*)(ws + WS_W + WS_WF);

  k_prep<<<PREP_INIT + PREP_W1 + PREP_W2, 256, 0, stream>>>(counts, perm, W1, W2, w1f, w2f);
  k_hist<<<B_ROWS / 256, 256, 0, stream>>>(eid, counts);
  k_scan<<<1, 64, 0, stream>>>(counts, base, cursor);
  k_scatter<<<B_ROWS / 256, 256, 0, stream>>>(eid, cursor, perm);
  k_adapter<<<NBLOCKS_MAIN, 512, 0, stream>>>(x, b1, b2, w1f, w2f, base, perm, out);
}

// Round 6
// 248.662 us; speedup vs baseline: 1.5594x; 1.1822x over previous
//
#include <hip/hip_runtime.h>

#define B_ROWS 32768
#define D_DIM 768
#define H_DIM 64
#define E_NUM 7
#define BM 16                                // rows per tile = one wave
#define PERM_CAP (B_ROWS + E_NUM * BM)       // 32880
#define NTILES (PERM_CAP / BM)               // 2055
#define W_ELEMS (E_NUM * D_DIM * H_DIM)

#define PREP_INIT ((PERM_CAP + 255) / 256)   // 129
#define PREP_W1 (E_NUM * 24)                 // 168
#define PREP_W2 (E_NUM * 12)                 // 84

// ---- ws layout (bytes) ----
#define WS_COUNTS 0
#define WS_BASE   64
#define WS_CURSOR 128
#define WS_PERM   256
#define WS_W      131840                     // 256 + 32880*4 = 131776, 256-aligned
#define WS_WF     1376256                    // 688128 shorts per packed weight buf
#define WS_NEEDED (WS_W + 2 * WS_WF)         // 2,884,352

typedef __attribute__((ext_vector_type(8))) short short8;
typedef __attribute__((ext_vector_type(8))) __bf16 bf16x8;
typedef __attribute__((ext_vector_type(4))) float f32x4;

__device__ __forceinline__ unsigned short f2bf(float f) {
  unsigned int u = __float_as_uint(f);
  unsigned int r = (u + 0x7fffu + ((u >> 16) & 1u)) >> 16;
  return (unsigned short)r;
}
__device__ __forceinline__ float bf2f(unsigned short s) {
  return __uint_as_float(((unsigned int)s) << 16);
}
__device__ __forceinline__ f32x4 mfma16(short8 a, short8 b, f32x4 c) {
  return __builtin_amdgcn_mfma_f32_16x16x32_bf16(
      __builtin_bit_cast(bf16x8, a), __builtin_bit_cast(bf16x8, b), c, 0, 0, 0);
}
__device__ __forceinline__ void gload_lds16(const float* g, void* l) {
  __builtin_amdgcn_global_load_lds(
      (const __attribute__((address_space(1))) unsigned int*)g,
      (__attribute__((address_space(3))) unsigned int*)l, 16, 0, 0);
}

// ---------------- prep: init + fragment-order weight packing ----------------
// w1f (shorts): ((((e*4+n)*24+kt)*2+plane)*64+lane)*8+j
//   elem = W1[e][d=kt*32+(lane>>4)*8+j][h=n*16+(lane&15)]
// w2f (shorts): ((((e*48+ct)*2+ks)*2+plane)*64+lane)*8+j
//   elem = W2[e][h=ks*32+(lane>>4)*8+j][d=ct*16+(lane&15)]
__global__ void k_prep(int* __restrict__ counts, int* __restrict__ perm,
                       const float* __restrict__ W1, const float* __restrict__ W2,
                       short* __restrict__ w1f, short* __restrict__ w2f) {
  __shared__ __align__(16) float tile[64][65];
  const int bid = blockIdx.x;
  const int t = threadIdx.x;

  if (bid < PREP_INIT) {
    int i = bid * 256 + t;
    if (i < PERM_CAP) perm[i] = -1;
    if (bid == 0 && t < 16) counts[t] = 0;
    return;
  }
  if (bid < PREP_INIT + PREP_W1) {
    const int b = bid - PREP_INIT;
    const int e = b / 24, kt = b % 24;
    {
      const int d = t >> 3, hc = (t & 7) * 8;
      const float* src = W1 + ((size_t)(e * D_DIM + kt * 32 + d)) * H_DIM + hc;
      f32x4 v0 = *reinterpret_cast<const f32x4*>(src);
      f32x4 v1 = *reinterpret_cast<const f32x4*>(src + 4);
#pragma unroll
      for (int i = 0; i < 4; ++i) {
        tile[d][hc + i] = v0[i];
        tile[d][hc + 4 + i] = v1[i];
      }
    }
    __syncthreads();
    {
      const int n = t >> 6, lane = t & 63;
      const int kgo = lane >> 4, l15o = lane & 15;
      short8 hi8, lo8;
#pragma unroll
      for (int j = 0; j < 8; ++j) {
        float v = tile[kgo * 8 + j][n * 16 + l15o];
        unsigned short h = f2bf(v);
        hi8[j] = (short)h;
        lo8[j] = (short)f2bf(v - bf2f(h));
      }
      short* dst = w1f + ((size_t)(((e * 4 + n) * 24 + kt) * 2) << 9) + (lane << 3);
      *reinterpret_cast<short8*>(dst) = hi8;
      *reinterpret_cast<short8*>(dst + 512) = lo8;
    }
    return;
  }
  {
    const int b = bid - PREP_INIT - PREP_W1;
    const int e = b / 12, ctb = b % 12;
    {
      const int h = t >> 2, dc = (t & 3) * 16;
      const float* src = W2 + ((size_t)(e * H_DIM + h)) * D_DIM + ctb * 64 + dc;
#pragma unroll
      for (int k = 0; k < 4; ++k) {
        f32x4 v = *reinterpret_cast<const f32x4*>(src + k * 4);
#pragma unroll
        for (int i = 0; i < 4; ++i) tile[h][dc + k * 4 + i] = v[i];
      }
    }
    __syncthreads();
    {
      const int ct4 = t >> 6, lane = t & 63;
      const int kgo = lane >> 4, l15o = lane & 15;
      const int ct = ctb * 4 + ct4;
#pragma unroll
      for (int ks = 0; ks < 2; ++ks) {
        short8 hi8, lo8;
#pragma unroll
        for (int j = 0; j < 8; ++j) {
          float v = tile[ks * 32 + kgo * 8 + j][ct4 * 16 + l15o];
          unsigned short h = f2bf(v);
          hi8[j] = (short)h;
          lo8[j] = (short)f2bf(v - bf2f(h));
        }
        short* dst = w2f + ((size_t)(((e * 48 + ct) * 2 + ks) * 2) << 9) + (lane << 3);
        *reinterpret_cast<short8*>(dst) = hi8;
        *reinterpret_cast<short8*>(dst + 512) = lo8;
      }
    }
    return;
  }
}

// ---------------- routing kernels ----------------
__global__ void k_hist(const int* __restrict__ eid, int* __restrict__ counts) {
  __shared__ int lc[E_NUM];
  if (threadIdx.x < E_NUM) lc[threadIdx.x] = 0;
  __syncthreads();
  int e = eid[blockIdx.x * 256 + threadIdx.x];
  e = e < 0 ? 0 : (e >= E_NUM ? E_NUM - 1 : e);
  atomicAdd(&lc[e], 1);
  __syncthreads();
  if (threadIdx.x < E_NUM) atomicAdd(&counts[threadIdx.x], lc[threadIdx.x]);
}

__global__ void k_scan(const int* __restrict__ counts, int* __restrict__ base,
                       int* __restrict__ cursor) {
  if (threadIdx.x == 0) {
    int run = 0;
    for (int e = 0; e < E_NUM; ++e) {
      base[e] = run;
      cursor[e] = run;
      run += ((counts[e] + BM - 1) / BM) * BM;
    }
    base[E_NUM] = run;
  }
}

__global__ void k_scatter(const int* __restrict__ eid, int* __restrict__ cursor,
                          int* __restrict__ perm) {
  __shared__ int lc[E_NUM];
  __shared__ int lb[E_NUM];
  if (threadIdx.x < E_NUM) lc[threadIdx.x] = 0;
  __syncthreads();
  int i = blockIdx.x * 256 + threadIdx.x;
  int e = eid[i];
  e = e < 0 ? 0 : (e >= E_NUM ? E_NUM - 1 : e);
  int lpos = atomicAdd(&lc[e], 1);
  __syncthreads();
  if (threadIdx.x < E_NUM) lb[threadIdx.x] = atomicAdd(&cursor[threadIdx.x], lc[threadIdx.x]);
  __syncthreads();
  perm[lb[e] + lpos] = i;
}

// ---------------- main fused kernel ----------------
// One wave (64 thr) per 16-row tile, one expert, full H and full 768 cols.
// No __syncthreads anywhere. GEMM1 x staged via global_load_lds (pair-of-kt
// granularity, dbuf, 1-pair-ahead, counted vmcnt). Weights in fragment order.
__global__ __launch_bounds__(64, 2) void k_adapter(
    const float* __restrict__ x, const float* __restrict__ b1,
    const float* __restrict__ b2, const short* __restrict__ w1f,
    const short* __restrict__ w2f, const int* __restrict__ base,
    const int* __restrict__ perm, float* __restrict__ out) {
  __shared__ __align__(16) float stg[2][2][16][32];  // 8KB: [buf][ktin][row][32f], 16B chunks swizzled
  __shared__ __align__(16) short hl_hi[16][72];
  __shared__ __align__(16) short hl_lo[16][72];
  __shared__ __align__(16) float ldsT[16][68];

  const int lane = threadIdx.x;
  const int l15 = lane & 15;
  const int kg = lane >> 4;
  const int m0 = blockIdx.x * BM;

  int e = 0;
#pragma unroll
  for (int i = 1; i < E_NUM; ++i)
    if (m0 >= base[i]) e = i;

  // per-lane staging sources: lane -> (row = ihalf*8 + (lane>>3), chunk = lane&7)
  // content of dest chunk c must be source chunk c ^ (row&7)  (bank swizzle)
  const int r8 = lane >> 3;
  int pr0 = perm[m0 + r8];
  int pr1 = perm[m0 + 8 + r8];
  if (pr0 < 0) pr0 = 0;
  if (pr1 < 0) pr1 = 0;
  const int sc = ((lane & 7) ^ r8) * 4;
  const float* sb0 = x + (size_t)pr0 * D_DIM + sc;
  const float* sb1 = x + (size_t)pr1 * D_DIM + sc;

  const short* w1e = w1f + (size_t)e * 98304;

#define STAGE_PAIR(p)                                                      \
  {                                                                        \
    char* db_ = (char*)&stg[(p) & 1][0][0][0];                             \
    const int k0_ = (p) * 64;                                              \
    gload_lds16(sb0 + k0_, db_ + lane * 16);                               \
    gload_lds16(sb1 + k0_, db_ + 1024 + lane * 16);                        \
    gload_lds16(sb0 + k0_ + 32, db_ + 2048 + lane * 16);                   \
    gload_lds16(sb1 + k0_ + 32, db_ + 3072 + lane * 16);                   \
  }

#define LOAD_W1(kt, dst)                                                   \
  {                                                                        \
    _Pragma("unroll") for (int n_ = 0; n_ < 4; ++n_) {                     \
      const short* p_ =                                                    \
          w1e + (((size_t)(n_ * 24 + (kt)) * 2) << 9) + (lane << 3);       \
      dst[n_][0] = *reinterpret_cast<const short8*>(p_);                   \
      dst[n_][1] = *reinterpret_cast<const short8*>(p_ + 512);             \
    }                                                                      \
  }

#define DO_KT(kt, w_)                                                      \
  {                                                                        \
    const int c0_ = (kg * 2) ^ (l15 & 7);                                  \
    const float* sp_ = &stg[((kt) >> 1) & 1][(kt)&1][l15][0];              \
    f32x4 va_ = *reinterpret_cast<const f32x4*>(sp_ + c0_ * 4);            \
    f32x4 vb_ = *reinterpret_cast<const f32x4*>(sp_ + (c0_ ^ 1) * 4);      \
    short8 ahi_, alo_;                                                     \
    _Pragma("unroll") for (int i_ = 0; i_ < 4; ++i_) {                     \
      unsigned short h0_ = f2bf(va_[i_]);                                  \
      ahi_[i_] = (short)h0_;                                               \
      alo_[i_] = (short)f2bf(va_[i_] - bf2f(h0_));                         \
      unsigned short h1_ = f2bf(vb_[i_]);                                  \
      ahi_[4 + i_] = (short)h1_;                                           \
      alo_[4 + i_] = (short)f2bf(vb_[i_] - bf2f(h1_));                     \
    }                                                                      \
    _Pragma("unroll") for (int n_ = 0; n_ < 4; ++n_) {                     \
      acc1[n_] = mfma16(ahi_, w_[n_][0], acc1[n_]);                        \
      acc1[n_] = mfma16(alo_, w_[n_][0], acc1[n_]);                        \
      acc1[n_] = mfma16(ahi_, w_[n_][1], acc1[n_]);                        \
    }                                                                      \
  }

  f32x4 acc1[4] = {{0.f, 0.f, 0.f, 0.f},
                   {0.f, 0.f, 0.f, 0.f},
                   {0.f, 0.f, 0.f, 0.f},
                   {0.f, 0.f, 0.f, 0.f}};
  short8 wA[4][2], wB[4][2];

  // prologue: stage pairs 0,1; load W1(kt=0)
  STAGE_PAIR(0);
  __builtin_amdgcn_sched_barrier(0);
  LOAD_W1(0, wA);
  __builtin_amdgcn_sched_barrier(0);
  STAGE_PAIR(1);
  __builtin_amdgcn_sched_barrier(0);

#pragma unroll
  for (int p = 0; p < 12; ++p) {
    // stage(p) guaranteed complete: >=12 younger VMEM ops exist past it
    asm volatile("s_waitcnt vmcnt(12)" ::: "memory");
    __builtin_amdgcn_sched_barrier(0);
    LOAD_W1(2 * p + 1, wB);          // next-kt weights (younger than stage p+1)
    DO_KT(2 * p, wA);                // compiler waits wA; stage(p+1) survives
    if (2 * p + 2 < 24) LOAD_W1(2 * p + 2, wA);
    DO_KT(2 * p + 1, wB);
    __builtin_amdgcn_sched_barrier(0);
    if (p + 2 < 12) STAGE_PAIR(p + 2);  // after last read of buf p&1
    __builtin_amdgcn_sched_barrier(0);
  }

  // bias + relu, split hi/lo, park in LDS (C-frag -> A-frag re-layout)
#pragma unroll
  for (int nn = 0; nn < 4; ++nn) {
    const int col = nn * 16 + l15;
    const float bv = b1[e * H_DIM + col];
#pragma unroll
    for (int j = 0; j < 4; ++j) {
      float v = acc1[nn][j] + bv;
      v = v > 0.f ? v : 0.f;
      unsigned short hh = f2bf(v);
      hl_hi[kg * 4 + j][col] = (short)hh;
      hl_lo[kg * 4 + j][col] = (short)f2bf(v - bf2f(hh));
    }
  }

  // ---- GEMM2: out[16 x 768] = relu(h) @ W2[e] + b2 + x ----
  short8 a2h[2], a2l[2];
#pragma unroll
  for (int ks = 0; ks < 2; ++ks) {
    a2h[ks] = *reinterpret_cast<const short8*>(&hl_hi[l15][ks * 32 + kg * 8]);
    a2l[ks] = *reinterpret_cast<const short8*>(&hl_lo[l15][ks * 32 + kg * 8]);
  }

  const short* w2e = w2f + (size_t)e * 98304;
#define W2P(ct_, ks_) (w2e + (((size_t)((ct_)*2 + (ks_)) * 2) << 9) + (lane << 3))

  const int tr = lane >> 2, cq = lane & 3;
  const int grow = perm[m0 + tr];
  const float* xr2 = x + (size_t)(grow < 0 ? 0 : grow) * D_DIM;
  float* orow = out + (size_t)(grow < 0 ? 0 : grow) * D_DIM;
  const float* b2e = b2 + e * D_DIM;

  short8 nwh = *reinterpret_cast<const short8*>(W2P(0, 0));
  short8 nwl = *reinterpret_cast<const short8*>(W2P(0, 0) + 512);
  f32x4 xva[4];
#pragma unroll
  for (int k = 0; k < 4; ++k)
    xva[k] = *reinterpret_cast<const f32x4*>(xr2 + cq * 16 + k * 4);

#pragma unroll
  for (int g = 0; g < 12; ++g) {
    f32x4 acc2[4];
#pragma unroll
    for (int t = 0; t < 8; ++t) {
      const int ct4 = t >> 1, ks = t & 1;
      short8 wh = nwh, wl = nwl;
      if (!(g == 11 && t == 7)) {
        const int t2 = t + 1;
        const int g2 = (t2 == 8) ? g + 1 : g;
        const int tt = t2 & 7;
        const int nct = g2 * 4 + (tt >> 1);
        const int nks = tt & 1;
        nwh = *reinterpret_cast<const short8*>(W2P(nct, nks));
        nwl = *reinterpret_cast<const short8*>(W2P(nct, nks) + 512);
      }
      if (ks == 0) acc2[ct4] = (f32x4){0.f, 0.f, 0.f, 0.f};
      acc2[ct4] = mfma16(a2h[ks], wh, acc2[ct4]);
      acc2[ct4] = mfma16(a2l[ks], wh, acc2[ct4]);
      acc2[ct4] = mfma16(a2h[ks], wl, acc2[ct4]);
    }
    // stash current residual regs, prefetch next group's residual
    f32x4 xcur[4];
#pragma unroll
    for (int k = 0; k < 4; ++k) xcur[k] = xva[k];
    if (g < 11) {
#pragma unroll
      for (int k = 0; k < 4; ++k)
        xva[k] = *reinterpret_cast<const f32x4*>(xr2 + (g + 1) * 64 + cq * 16 + k * 4);
    }
    // per-wave transpose via LDS: lane -> 16 consecutive cols of one row
#pragma unroll
    for (int ct4 = 0; ct4 < 4; ++ct4)
#pragma unroll
      for (int j = 0; j < 4; ++j) ldsT[kg * 4 + j][ct4 * 16 + l15] = acc2[ct4][j];

    const int colbase = g * 64 + cq * 16;
    if (grow >= 0) {
#pragma unroll
      for (int k = 0; k < 4; ++k) {
        f32x4 y = *reinterpret_cast<const f32x4*>(&ldsT[tr][cq * 16 + k * 4]);
        f32x4 bv = *reinterpret_cast<const f32x4*>(b2e + colbase + k * 4);
        f32x4 o = y + bv + xcur[k];
        *reinterpret_cast<f32x4*>(orow + colbase + k * 4) = o;
      }
    }
  }
#undef W1P
#undef W2P
#undef STAGE_PAIR
#undef LOAD_W1
#undef DO_KT
}

// ---------------- fp32 fallback (used only if ws too small) ----------------
__global__ void k_fallback(const float* __restrict__ x, const int* __restrict__ eid,
                           const float* __restrict__ W1, const float* __restrict__ b1,
                           const float* __restrict__ W2, const float* __restrict__ b2,
                           float* __restrict__ out) {
  __shared__ float xs[D_DIM];
  __shared__ float hs[H_DIM];
  const int row = blockIdx.x;
  int e = eid[row];
  e = e < 0 ? 0 : (e >= E_NUM ? E_NUM - 1 : e);
  const float* xr = x + (size_t)row * D_DIM;
  for (int i = threadIdx.x; i < D_DIM; i += 256) xs[i] = xr[i];
  __syncthreads();
  if (threadIdx.x < H_DIM) {
    const float* w = W1 + (size_t)e * D_DIM * H_DIM + threadIdx.x;
    float acc = b1[e * H_DIM + threadIdx.x];
    for (int d = 0; d < D_DIM; ++d) acc += xs[d] * w[(size_t)d * H_DIM];
    hs[threadIdx.x] = acc > 0.f ? acc : 0.f;
  }
  __syncthreads();
  for (int c = threadIdx.x; c < D_DIM; c += 256) {
    const float* w = W2 + (size_t)e * H_DIM * D_DIM + c;
    float acc = b2[e * D_DIM + c];
    for (int h = 0; h < H_DIM; ++h) acc += hs[h] * w[(size_t)h * D_DIM];
    out[(size_t)row * D_DIM + c] = xs[c] + acc;
  }
}

extern "C" void kernel_launch(void* const* d_in, const int* in_sizes, int n_in,
                              void* d_out, int out_size, void* d_ws, size_t ws_size,
                              hipStream_t stream) {
  const float* x = (const float*)d_in[0];
  const int* eid = (const int*)d_in[1];
  const float* W1 = (const float*)d_in[2];
  const float* b1 = (const float*)d_in[3];
  const float* W2 = (const float*)d_in[4];
  const float* b2 = (const float*)d_in[5];
  float* out = (float*)d_out;

  if (ws_size < (size_t)WS_NEEDED) {
    k_fallback<<<B_ROWS, 256, 0, stream>>>(x, eid, W1, b1, W2, b2, out);
    return;
  }

  char* ws = (char*)d_ws;
  int* counts = (int*)(ws + WS_COUNTS);
  int* base = (int*)(ws + WS_BASE);
  int* cursor = (int*)(ws + WS_CURSOR);
  int* perm = (int*)(ws + WS_PERM);
  short* w1f = (short*)(ws + WS_W);
  short* w2f = (short*)(ws + WS_W + WS_WF);

  k_prep<<<PREP_INIT + PREP_W1 + PREP_W2, 256, 0, stream>>>(counts, perm, W1, W2, w1f, w2f);
  k_hist<<<B_ROWS / 256, 256, 0, stream>>>(eid, counts);
  k_scan<<<1, 64, 0, stream>>>(counts, base, cursor);
  k_scatter<<<B_ROWS / 256, 256, 0, stream>>>(eid, cursor, perm);
  k_adapter<<<NTILES, 64, 0, stream>>>(x, b1, b2, w1f, w2f, base, perm, out);
}